// Round 10
// baseline (46.576 us; speedup 1.0000x reference)
//
#include <hip/hip_runtime.h>
#include <math.h>

#define GEO_N 256

// Single-instruction HW approximations (~1 ulp) — error budget is huge
// (threshold 1.6e-2, measured absmax 0.0 with these in r9).
__device__ __forceinline__ float frcp(float x) { return __builtin_amdgcn_rcpf(x); }
__device__ __forceinline__ float frsq(float x) { return __builtin_amdgcn_rsqf(x); }
__device__ __forceinline__ float fsqrtf_(float x) { return __builtin_amdgcn_sqrtf(x); }

__device__ __forceinline__ float wredf(float v) {
#pragma unroll
  for (int off = 32; off; off >>= 1) v += __shfl_xor(v, off, 64);
  return v;
}

// Branchless fast Jacobi rotation (both sides) + accumulate into V. r9-validated.
template <int P, int Q>
__device__ __forceinline__ void jrot(float G[3][3], float V[3][3]) {
  const float apq = G[P][Q];
  const float tau = (G[Q][Q] - G[P][P]) * 0.5f * frcp(apq);
  const float tt = fsqrtf_(1.0f + tau * tau);
  const float tr = frcp(tau + copysignf(tt, tau));
  const float cr = frsq(1.0f + tr * tr);
  const bool skip = fabsf(apq) < 1e-30f;
  const float c = skip ? 1.0f : cr;
  const float s = skip ? 0.0f : tr * cr;
#pragma unroll
  for (int k = 0; k < 3; ++k) {
    float gkp = G[k][P], gkq = G[k][Q];
    G[k][P] = c * gkp - s * gkq;
    G[k][Q] = s * gkp + c * gkq;
  }
#pragma unroll
  for (int k = 0; k < 3; ++k) {
    float gpk = G[P][k], gqk = G[Q][k];
    G[P][k] = c * gpk - s * gqk;
    G[Q][k] = s * gpk + c * gqk;
  }
#pragma unroll
  for (int k = 0; k < 3; ++k) {
    float vkp = V[k][P], vkq = V[k][Q];
    V[k][P] = c * vkp - s * vkq;
    V[k][Q] = s * vkp + c * vkq;
  }
}

// From 16 raw moment sums -> R(9), scale, T(3) packed into bc[0..12].
// Fast-math, fixed 4 sweeps. Validated r9 (absmax 0.0).
__device__ __forceinline__ void solve_rst(const float s0[16], float bc[13]) {
  const float invN = 1.0f / (float)GEO_N;
  const float smx = s0[0] * invN, smy = s0[1] * invN, smz = s0[2] * invN;
  const float dmx = s0[3] * invN, dmy = s0[4] * invN, dmz = s0[5] * invN;
  float A[3][3];
  A[0][0] = s0[6] * invN - dmx * smx;  A[0][1] = s0[7] * invN - dmx * smy;  A[0][2] = s0[8] * invN - dmx * smz;
  A[1][0] = s0[9] * invN - dmy * smx;  A[1][1] = s0[10] * invN - dmy * smy; A[1][2] = s0[11] * invN - dmy * smz;
  A[2][0] = s0[12] * invN - dmz * smx; A[2][1] = s0[13] * invN - dmz * smy; A[2][2] = s0[14] * invN - dmz * smz;
  const float var_sum = s0[15] * invN - (smx * smx + smy * smy + smz * smz);

  float G[3][3];
#pragma unroll
  for (int i = 0; i < 3; ++i)
#pragma unroll
    for (int j = 0; j < 3; ++j)
      G[i][j] = A[0][i] * A[0][j] + A[1][i] * A[1][j] + A[2][i] * A[2][j];
  float V[3][3] = {{1, 0, 0}, {0, 1, 0}, {0, 0, 1}};
#pragma unroll
  for (int sweep = 0; sweep < 4; ++sweep) {
    jrot<0, 1>(G, V);
    jrot<0, 2>(G, V);
    jrot<1, 2>(G, V);
  }
  float l0 = G[0][0], l1 = G[1][1], l2 = G[2][2];
  if (l0 < l1) { float tl = l0; l0 = l1; l1 = tl;
#pragma unroll
    for (int k = 0; k < 3; ++k) { float tv = V[k][0]; V[k][0] = V[k][1]; V[k][1] = tv; } }
  if (l0 < l2) { float tl = l0; l0 = l2; l2 = tl;
#pragma unroll
    for (int k = 0; k < 3; ++k) { float tv = V[k][0]; V[k][0] = V[k][2]; V[k][2] = tv; } }
  if (l1 < l2) { float tl = l1; l1 = l2; l2 = tl;
#pragma unroll
    for (int k = 0; k < 3; ++k) { float tv = V[k][1]; V[k][1] = V[k][2]; V[k][2] = tv; } }
  const float sig0 = fsqrtf_(fmaxf(l0, 0.0f));
  const float sig1 = fsqrtf_(fmaxf(l1, 0.0f));
  const float sig2 = fsqrtf_(fmaxf(l2, 0.0f));

  float v0[3] = {V[0][0], V[1][0], V[2][0]};
  float v1[3] = {V[0][1], V[1][1], V[2][1]};
  float v2[3] = {V[0][2], V[1][2], V[2][2]};
  float u0[3], u1[3], u2r[3];
#pragma unroll
  for (int i = 0; i < 3; ++i) {
    u0[i]  = A[i][0] * v0[0] + A[i][1] * v0[1] + A[i][2] * v0[2];
    u1[i]  = A[i][0] * v1[0] + A[i][1] * v1[1] + A[i][2] * v1[2];
    u2r[i] = A[i][0] * v2[0] + A[i][1] * v2[1] + A[i][2] * v2[2];
  }
  float n0 = u0[0] * u0[0] + u0[1] * u0[1] + u0[2] * u0[2];
  if (n0 > 1e-28f) { float inv = frsq(n0); u0[0] *= inv; u0[1] *= inv; u0[2] *= inv; }
  else { u0[0] = 1.0f; u0[1] = 0.0f; u0[2] = 0.0f; }
  float d01 = u1[0] * u0[0] + u1[1] * u0[1] + u1[2] * u0[2];
  u1[0] -= d01 * u0[0]; u1[1] -= d01 * u0[1]; u1[2] -= d01 * u0[2];
  float n1 = u1[0] * u1[0] + u1[1] * u1[1] + u1[2] * u1[2];
  if (n1 > 1e-28f) { float inv = frsq(n1); u1[0] *= inv; u1[1] *= inv; u1[2] *= inv; }
  else {
    float ex[3] = {1, 0, 0}, ey[3] = {0, 1, 0};
    const float* e = (fabsf(u0[0]) < 0.9f) ? ex : ey;
    u1[0] = u0[1] * e[2] - u0[2] * e[1];
    u1[1] = u0[2] * e[0] - u0[0] * e[2];
    u1[2] = u0[0] * e[1] - u0[1] * e[0];
    float nn = u1[0] * u1[0] + u1[1] * u1[1] + u1[2] * u1[2];
    float inv = frsq(nn);
    u1[0] *= inv; u1[1] *= inv; u1[2] *= inv;
  }
  float u2[3] = {u0[1] * u1[2] - u0[2] * u1[1],
                 u0[2] * u1[0] - u0[0] * u1[2],
                 u0[0] * u1[1] - u0[1] * u1[0]};
  float d2 = u2[0] * u2r[0] + u2[1] * u2r[1] + u2[2] * u2r[2];
  if (d2 < 0.0f) { u2[0] = -u2[0]; u2[1] = -u2[1]; u2[2] = -u2[2]; }

  const float scale = (sig0 + sig1 + sig2) * frcp(fmaxf(var_sum, 1e-30f));
  float R[3][3];
#pragma unroll
  for (int i = 0; i < 3; ++i)
#pragma unroll
    for (int j = 0; j < 3; ++j)
      R[i][j] = u0[i] * v0[j] + u1[i] * v1[j] + u2[i] * v2[j];
  const float Tx = dmx - scale * (R[0][0] * smx + R[0][1] * smy + R[0][2] * smz);
  const float Ty = dmy - scale * (R[1][0] * smx + R[1][1] * smy + R[1][2] * smz);
  const float Tz = dmz - scale * (R[2][0] * smx + R[2][1] * smy + R[2][2] * smz);
#pragma unroll
  for (int i = 0; i < 3; ++i)
#pragma unroll
    for (int j = 0; j < 3; ++j) bc[3 * i + j] = R[i][j];
  bc[9] = scale; bc[10] = Tx; bc[11] = Ty; bc[12] = Tz;
}

// ---------- Single-pass, barrier-free, shuffle-minimal. ----------
// One WAVE = 4 batches. Lane l owns batch g=l>>4, points [q*16, q*16+16)
// (q=l&15): 12 contiguous float4 per side per lane. Moments reduce is a
// 4-stage halving butterfly WITHIN the 16-lane group (15 shfl); 16-shfl
// gather gives each lane its own batch's 16 moments; solve per lane; the
// error phase then uses the lane's OWN params on its OWN points: 0 shfl.
// Total 37 shfl/wave vs 142 in r9.
__global__ __launch_bounds__(256) void geo_wave4t(const float* __restrict__ kp,
                                                  const int* __restrict__ perm,
                                                  float* __restrict__ partials,
                                                  int B, int NW) {
  const int wid = (blockIdx.x << 2) | (threadIdx.x >> 6);
  if (wid >= NW) return;  // no barriers -> early return safe
  const int lane = threadIdx.x & 63;
  const int g = lane >> 4, q = lane & 15;
  const int b0 = wid * 4;
  const int bi = b0 + g;
  const int bb = min(bi, B - 1);
  const float4* base = (const float4*)kp;

  const int pm = perm[bb];

  // ---- Load own slice: 24 contiguous-float4 loads in flight ----
  const float4* s4 = base + (size_t)bb * 192 + q * 12;
  const float4* d4 = base + (size_t)pm * 192 + q * 12;
  float4 S[12], D[12];
#pragma unroll
  for (int j = 0; j < 12; ++j) S[j] = s4[j];
#pragma unroll
  for (int j = 0; j < 12; ++j) D[j] = d4[j];

  float s[48], d[48];
#pragma unroll
  for (int j = 0; j < 12; ++j) {
    s[4 * j + 0] = S[j].x; s[4 * j + 1] = S[j].y; s[4 * j + 2] = S[j].z; s[4 * j + 3] = S[j].w;
    d[4 * j + 0] = D[j].x; d[4 * j + 1] = D[j].y; d[4 * j + 2] = D[j].z; d[4 * j + 3] = D[j].w;
  }

  // ---- Per-lane partial moments over 16 points ----
  float r[16];
#pragma unroll
  for (int k = 0; k < 16; ++k) r[k] = 0.0f;
#pragma unroll
  for (int p = 0; p < 16; ++p) {
    const float sx = s[3 * p + 0], sy = s[3 * p + 1], sz = s[3 * p + 2];
    const float dx = d[3 * p + 0], dy = d[3 * p + 1], dz = d[3 * p + 2];
    r[0] += sx; r[1] += sy; r[2] += sz;
    r[3] += dx; r[4] += dy; r[5] += dz;
    r[6] += dx * sx; r[7] += dx * sy; r[8] += dx * sz;
    r[9] += dy * sx; r[10] += dy * sy; r[11] += dy * sz;
    r[12] += dz * sx; r[13] += dz * sy; r[14] += dz * sz;
    r[15] += sx * sx + sy * sy + sz * sz;
  }

  // ---- 4-stage halving reduce within the 16-lane group (xor 1,2,4,8) ----
  // Ends with lane (g,q) holding moment bitrev4(q) of batch g. Construction
  // identical to the r6-r9-validated hred16, truncated to 4 stages.
  const int b1 = q & 1, b2 = (q >> 1) & 1, b3 = (q >> 2) & 1, b4 = (q >> 3) & 1;
  float v8[8], v4[4], v2[2], parked;
#pragma unroll
  for (int k = 0; k < 8; ++k) {
    float send = b1 ? r[k] : r[k + 8];
    float recv = __shfl_xor(send, 1, 64);
    v8[k] = (b1 ? r[k + 8] : r[k]) + recv;
  }
#pragma unroll
  for (int k = 0; k < 4; ++k) {
    float send = b2 ? v8[k] : v8[k + 4];
    float recv = __shfl_xor(send, 2, 64);
    v4[k] = (b2 ? v8[k + 4] : v8[k]) + recv;
  }
#pragma unroll
  for (int k = 0; k < 2; ++k) {
    float send = b3 ? v4[k] : v4[k + 2];
    float recv = __shfl_xor(send, 4, 64);
    v2[k] = (b3 ? v4[k + 2] : v4[k]) + recv;
  }
  {
    float send = b4 ? v2[0] : v2[1];
    float recv = __shfl_xor(send, 8, 64);
    parked = (b4 ? v2[1] : v2[0]) + recv;
  }

  // ---- Gather: lane collects its own batch's 16 moments (16 shfl) ----
  // Moment k of batch g sits at lane (g<<4) | bitrev4(k).
  constexpr int br[16] = {0, 8, 4, 12, 2, 10, 6, 14, 1, 9, 5, 13, 3, 11, 7, 15};
  float s0[16];
#pragma unroll
  for (int k = 0; k < 16; ++k)
    s0[k] = __shfl(parked, (lane & 0x30) | br[k], 64);

  // ---- Solve (each lane solves its own batch; 16x redundant, 1 issue cost) ----
  float bc[13];
  solve_rst(s0, bc);

  // ---- Errors: own params on own points — zero shuffles ----
  float acc = 0.0f;
#pragma unroll
  for (int p = 0; p < 16; ++p) {
    const float sx = s[3 * p + 0], sy = s[3 * p + 1], sz = s[3 * p + 2];
    const float dx = d[3 * p + 0], dy = d[3 * p + 1], dz = d[3 * p + 2];
    const float e0 = bc[9] * (bc[0] * sx + bc[1] * sy + bc[2] * sz) + bc[10] - dx;
    const float e1 = bc[9] * (bc[3] * sx + bc[4] * sy + bc[5] * sz) + bc[11] - dy;
    const float e2 = bc[9] * (bc[6] * sx + bc[7] * sy + bc[8] * sz) + bc[12] - dz;
    acc += fabsf(e0) + fabsf(e1) + fabsf(e2);
  }
  if (bi >= B) acc = 0.0f;  // mask clamped tail batches (B%4==0 -> never here)

  acc = wredf(acc);
  if (lane == 0) partials[wid] = acc;
}

// ---------- Final reduce ----------
__global__ __launch_bounds__(1024) void geo_fin(const float* __restrict__ partials,
                                                float* __restrict__ out, int n,
                                                double inv_total) {
  const int t = threadIdx.x;
  double acc = 0.0;
  for (int i = t; i < n; i += 1024) acc += (double)partials[i];
#pragma unroll
  for (int off = 32; off; off >>= 1) acc += __shfl_xor(acc, off, 64);
  __shared__ double sred[16];
  if ((t & 63) == 0) sred[t >> 6] = acc;
  __syncthreads();
  if (t == 0) {
    double tot = 0.0;
#pragma unroll
    for (int k = 0; k < 16; ++k) tot += sred[k];
    out[0] = (float)(tot * inv_total);
  }
}

extern "C" void kernel_launch(void* const* d_in, const int* in_sizes, int n_in,
                              void* d_out, int out_size, void* d_ws, size_t ws_size,
                              hipStream_t stream) {
  const float* kp = (const float*)d_in[0];
  const int* perm = (const int*)d_in[1];
  float* out = (float*)d_out;
  const int B = in_sizes[1];
  const double inv_total = 1.0 / ((double)B * (double)GEO_N * 3.0);

  const int NW = (B + 3) / 4;      // one wave per 4 batches
  float* partials = (float*)d_ws;  // NW floats
  const int grid = (NW + 3) / 4;   // 4 waves per 256-thread block
  geo_wave4t<<<grid, 256, 0, stream>>>(kp, perm, partials, B, NW);
  geo_fin<<<1, 1024, 0, stream>>>(partials, out, NW, inv_total);
}